// Round 3
// baseline (276.211 us; speedup 1.0000x reference)
//
#include <hip/hip_runtime.h>
#include <stdint.h>

#define D_EMB 1024
#define NBATCH 8
#define SEQ 2048
#define MTOT (NBATCH*SEQ)   // 16384

typedef __attribute__((ext_vector_type(8))) short short8;
typedef __attribute__((ext_vector_type(4))) float f32x4;

__device__ __forceinline__ ushort bf16r(float x) {
  union { float f; uint32_t u; } c; c.f = x;
  return (ushort)((c.u + 0x7fffu + ((c.u >> 16) & 1u)) >> 16);
}

// async 16B/lane global->LDS (LDS dest must be wave-uniform base + lane*16)
__device__ __forceinline__ void cp16(const ushort* g, ushort* l) {
  __builtin_amdgcn_global_load_lds(
      (const __attribute__((address_space(1))) void*)g,
      (__attribute__((address_space(3))) void*)l, 16, 0, 0);
}

// merged: blocks <4096: wave-per-row cvt x->bf16 + vw[row]=x.wv_eff+sc[1]
//         blocks >=4096: cvt Wattn rows 0..2047 -> bf16 (q,k weights)
__global__ __launch_bounds__(256) void cvt_all(
    const float4* __restrict__ x4, const float4* __restrict__ W4,
    const float4* __restrict__ wv4, const float* __restrict__ sc,
    ushort* __restrict__ xb, ushort* __restrict__ wqkb, float* __restrict__ vw) {
  int tid = threadIdx.x;
  if (blockIdx.x < 4096) {
    int wave = tid >> 6, lane = tid & 63;
    long row = (long)blockIdx.x * 4 + wave;
    const float4* xr = x4 + row * 256;
    ushort* xo = xb + row * D_EMB;
    float s = 0.f;
    #pragma unroll
    for (int i = 0; i < 4; i++) {
      int idx = lane + i * 64;
      float4 v = xr[idx];
      float4 w = wv4[idx];
      *(ushort4*)(xo + idx * 4) = make_ushort4(bf16r(v.x), bf16r(v.y), bf16r(v.z), bf16r(v.w));
      s += v.x * w.x + v.y * w.y + v.z * w.z + v.w * w.w;
    }
    #pragma unroll
    for (int off = 32; off; off >>= 1) s += __shfl_xor(s, off);
    if (lane == 0) vw[row] = s + sc[1];
  } else {
    long base = (long)(blockIdx.x - 4096) * 1024 + tid;   // in float4 units
    #pragma unroll
    for (int i = 0; i < 4; i++) {
      long idx = base + i * 256;
      float4 v = W4[idx];
      *(ushort4*)(wqkb + idx * 4) = make_ushort4(bf16r(v.x), bf16r(v.y), bf16r(v.z), bf16r(v.w));
    }
  }
}

// init: b0 zero w_eff, b1 zero wv_eff, b2 sc[0]=bp.Wfc+bfc, b3..34 zero num/den (32768 f32)
__global__ void init_kernel(const float* __restrict__ bp, const float* __restrict__ Wfc,
                            const float* __restrict__ bfc,
                            float* __restrict__ w_eff, float* __restrict__ wv_eff,
                            float* __restrict__ numden, float* __restrict__ sc) {
  int tid = threadIdx.x;
  int b = blockIdx.x;
  if (b == 0) { w_eff[tid] = 0.f; return; }
  if (b == 1) { wv_eff[tid] = 0.f; return; }
  if (b >= 3) { numden[(long)(b - 3) * 1024 + tid] = 0.f; return; }
  float v = bp[tid] * Wfc[tid];
  int lane = tid & 63, w = tid >> 6;
  #pragma unroll
  for (int off = 32; off; off >>= 1) v += __shfl_xor(v, off);
  __shared__ float red[16];
  if (lane == 0) red[w] = v;
  __syncthreads();
  if (tid == 0) {
    float s = 0.f;
    #pragma unroll
    for (int i = 0; i < 16; i++) s += red[i];
    sc[0] = s + bfc[0];
  }
}

// w_eff[c] += sum over 16-d-chunk of Wfc[d]*Wp[d,c]   grid(4,64)
__global__ void prep1(const float* __restrict__ Wp, const float* __restrict__ Wfc,
                      float* __restrict__ w_eff) {
  int c = blockIdx.x * 256 + threadIdx.x;
  int d0 = blockIdx.y * 16;
  float s = 0.f;
  #pragma unroll
  for (int d = d0; d < d0 + 16; d++) s += Wfc[d] * Wp[(long)d * D_EMB + c];
  atomicAdd(&w_eff[c], s);
}

// grid(4,65): by<64 -> wv_eff[d] += sum over 16-c-chunk of w_eff[c]*Wattn[2048+c, d]
//             by==64 (bx==0) -> sc[1] = sum_c battn[2048+c]*w_eff[c]
__global__ void prep2(const float* __restrict__ Wattn, const float* __restrict__ battn,
                      const float* __restrict__ w_eff, float* __restrict__ wv_eff,
                      float* __restrict__ sc) {
  int tid = threadIdx.x;
  if (blockIdx.y == 64) {
    if (blockIdx.x != 0) return;
    float v = 0.f;
    #pragma unroll
    for (int i = 0; i < 4; i++) { int c = tid + i * 256; v += battn[2048 + c] * w_eff[c]; }
    int lane = tid & 63, w = tid >> 6;
    #pragma unroll
    for (int off = 32; off; off >>= 1) v += __shfl_xor(v, off);
    __shared__ float red[4];
    if (lane == 0) red[w] = v;
    __syncthreads();
    if (tid == 0) sc[1] = red[0] + red[1] + red[2] + red[3];
    return;
  }
  int d = blockIdx.x * 256 + tid;
  int c0 = blockIdx.y * 16;
  float s = 0.f;
  #pragma unroll
  for (int c = c0; c < c0 + 16; c++) s += w_eff[c] * Wattn[(long)(2048 + c) * D_EMB + d];
  atomicAdd(&wv_eff[d], s);
}

// ------------- NT GEMM: 256x256 tile, BK=64, m201-faithful 4-quadrant phases -------------
// 512 thr = 8 waves (2M x 4N); per-wave out 128x64 = 8x4 frags; 16x16x32 bf16 MFMA.
// LDS 128KiB: A buf0 [0,16K) ushorts, A buf1 [16K,32K), B buf0 [32K,48K), B buf1 [48K,64K);
//   each region 256 rows x 64 k, chunk-swizzle stored_chunk = chunk ^ (row&7) (G4 fix; applied
//   via pre-swizzled GLOBAL src + linear cp16 dest, XOR'd ds_read — rule #21 both-sides).
// Per K-tile u (buf=u&1): 4 quadrant phases, each {ds_reads; 1 half-tile stage (2 cp16);
//   barrier; lgkmcnt(0); setprio(1) 16 MFMA setprio(0); [vmcnt(4) at P4]; barrier}:
//   P1: read af(qa0)+bf0(qb0) [12]; stage Ah0(u+1)->other buf;  MFMA Q(0,0)
//   P2: read bf1(qb1)          [4]; stage Ah1(u+1)->other buf;  MFMA Q(0,1)  (af reused)
//   P3: read af(qa1)           [8]; stage Bh0(u+2)->same buf;   MFMA Q(1,1)  (bf1 reused)
//   P4: no reads               [0]; stage Bh1(u+2)->same buf;   MFMA Q(1,0)  (bf0 reused); VM4
// Hazards verified: A-halves of a buf last read at P3 (by their wm-waves), staged next tile's
//   P1/P2 (barrier-separated); B-halves last read at P2 (by their wn-waves), staged P3/P4 same
//   tile. vmcnt(4) at P4(u) forces A(u+1) (issued P1/P2(u)) + B(u+1) (issued P3/P4(u-1))
//   retired before P1(u+1); only B(u+2) (P3/P4(u)) stays in flight — counted, never 0 (T4).
// FUSED=false: C[m,n] = bf16(scale*acc + bias[n])   (GEMM1 -> qk)
// FUSED=true : per-row partial softmax: num[m] += sum_n exp(scale*acc)*vw[n], den[m] += sum_n exp
template<bool FUSED, bool REMAP>
__global__ __launch_bounds__(512, 2) void gemm_nt(
    const ushort* __restrict__ A, long lda, long sAz,
    const ushort* __restrict__ B, long ldb, long sBz,
    ushort* __restrict__ C, long ldc,
    const float* __restrict__ bias, float scale, int K,
    const float* __restrict__ vw, float* __restrict__ num, float* __restrict__ den) {
  __shared__ __align__(16) ushort lds[65536];

  int bx, by, z;
  if (REMAP) {
    // GEMM1 grid (8,64): flat%8 = XCD (m09 round-robin). XCD k owns M-stripe by in [8k,8k+8).
    int f = (int)(blockIdx.x + 8u * blockIdx.y);
    int xcd = f & 7, g = f >> 3;
    bx = g & 7; by = xcd * 8 + (g >> 3); z = 0;
  } else {
    bx = blockIdx.x; by = blockIdx.y; z = blockIdx.z;
  }

  const ushort* Az = A + (long)z * sAz;
  const ushort* Bz = B + (long)z * sBz;
  long m0 = (long)by * 256, n0 = (long)bx * 256;
  int t = threadIdx.x;
  int wave = t >> 6, lane = t & 63;
  int r = lane & 15, q = lane >> 4;
  int wm = wave >> 2, wn = wave & 3;     // wave rows [wm*128,+128), cols [wn*64,+64)

  f32x4 acc[8][4] = {};

  // ---- staging addressing: thread covers slots t (rows 0..63 of a half) and t+512 (64..127)
  int rl = t >> 3;                       // local row in half-tile, 0..63
  int cs = t & 7;                        // stored 16B-chunk
  int gc = cs ^ (rl & 7);                // global chunk (pre-swizzled source, rule #21)
  const ushort* pA = Az + (m0 + rl) * lda + gc * 8;
  const ushort* pB = Bz + (n0 + rl) * ldb + gc * 8;
  long a64 = 64 * lda, a128 = 128 * lda;
  long b64 = 64 * ldb, b128s = 128 * ldb;
  int dst = t * 8;                       // linear LDS dest (ushort units) within half-region

  // ---- ds_read addressing (region-relative, ushort units)
  int sw8 = (q ^ (r & 7)) * 8;           // stored chunk for logical chunk q (kk=0); kk=1 = ^32
  int aoff = (wm * 128 + r) * 64 + sw8;
  int boff = (wn * 64 + r) * 64 + sw8;

  int NT = K >> 6;                       // 16 for K=1024 (even, >=4)

#define STG_A(BUF, H, TT) do { \
    cp16(pA + (long)(TT) * 64 + (H) * a128,       lds + (BUF) * 16384 + (H) * 8192 + dst); \
    cp16(pA + (long)(TT) * 64 + (H) * a128 + a64, lds + (BUF) * 16384 + (H) * 8192 + 4096 + dst); \
  } while (0)
#define STG_B(BUF, H, TT) do { \
    cp16(pB + (long)(TT) * 64 + (H) * b128s,       lds + 32768 + (BUF) * 16384 + (H) * 8192 + dst); \
    cp16(pB + (long)(TT) * 64 + (H) * b128s + b64, lds + 32768 + (BUF) * 16384 + (H) * 8192 + 4096 + dst); \
  } while (0)

#define LDA_Q(BUF, QA) do { \
    _Pragma("unroll") \
    for (int i = 0; i < 4; i++) { \
      af[0][i] = *(const short8*)(lds + (BUF) * 16384 + ( aoff + (QA) * 4096 + i * 1024       )); \
      af[1][i] = *(const short8*)(lds + (BUF) * 16384 + ((aoff + (QA) * 4096 + i * 1024) ^ 32 )); \
    } \
  } while (0)
#define LDB_Q(BUF, QB, BF) do { \
    _Pragma("unroll") \
    for (int j = 0; j < 2; j++) { \
      BF[0][j] = *(const short8*)(lds + 32768 + (BUF) * 16384 + ( boff + (QB) * 2048 + j * 1024       )); \
      BF[1][j] = *(const short8*)(lds + 32768 + (BUF) * 16384 + ((boff + (QB) * 2048 + j * 1024) ^ 32 )); \
    } \
  } while (0)

#define MM_Q(QA, QB, BF) do { \
    __builtin_amdgcn_s_setprio(1); \
    _Pragma("unroll") \
    for (int kk = 0; kk < 2; kk++) { \
      _Pragma("unroll") \
      for (int i = 0; i < 4; i++) { \
        _Pragma("unroll") \
        for (int j = 0; j < 2; j++) \
          acc[(QA) * 4 + i][(QB) * 2 + j] = __builtin_amdgcn_mfma_f32_16x16x32_bf16( \
              af[kk][i], BF[kk][j], acc[(QA) * 4 + i][(QB) * 2 + j], 0, 0, 0); \
      } \
    } \
    __builtin_amdgcn_s_setprio(0); \
  } while (0)

#define BAR __builtin_amdgcn_s_barrier()
#define LGKM0 asm volatile("s_waitcnt lgkmcnt(0)" ::: "memory")
#define VM4 asm volatile("s_waitcnt vmcnt(4)" ::: "memory")
#define VM0 asm volatile("s_waitcnt vmcnt(0)" ::: "memory")

  // TILE(BUF, OB, TT, DOA, DOB, P4WAIT): 4 quadrant phases of K-tile TT read from buf BUF;
  //   DOA: stage A-halves of tile TT+1 into OB; DOB: stage B-halves of tile TT+2 into BUF.
#define TILE(BUF, OB, TT, DOA, DOB, P4WAIT) do { \
    short8 af[2][4], bf0[2][2], bf1[2][2]; \
    /* P1 */ \
    LDA_Q(BUF, 0); LDB_Q(BUF, 0, bf0); \
    if (DOA) STG_A(OB, 0, (TT) + 1); \
    BAR; LGKM0; MM_Q(0, 0, bf0); BAR; \
    /* P2 */ \
    LDB_Q(BUF, 1, bf1); \
    if (DOA) STG_A(OB, 1, (TT) + 1); \
    BAR; LGKM0; MM_Q(0, 1, bf1); BAR; \
    /* P3 */ \
    LDA_Q(BUF, 1); \
    if (DOB) STG_B(BUF, 0, (TT) + 2); \
    BAR; LGKM0; MM_Q(1, 1, bf1); BAR; \
    /* P4 */ \
    if (DOB) STG_B(BUF, 1, (TT) + 2); \
    BAR; MM_Q(1, 0, bf0); P4WAIT; BAR; \
  } while (0)

  // prologue: tile0 full (8 cp16) + tile1 B-halves (4 cp16); A(1) comes from P1/P2 of tile0.
  STG_A(0, 0, 0); STG_A(0, 1, 0); STG_B(0, 0, 0); STG_B(0, 1, 0);
  STG_B(1, 0, 1); STG_B(1, 1, 1);
  VM4;                                   // tile0 landed; tile1's B (4) may remain in flight
  BAR;

  // main: tiles 0..NT-3 uniform (NT-2 tiles, even count), then peel NT-2, NT-1.
  #pragma unroll 1
  for (int u = 0; u < NT - 2; u += 2) {
    TILE(0, 1, u,     true, true, VM4);
    TILE(1, 0, u + 1, true, true, VM4);
  }
  TILE(0, 1, NT - 2, true,  false, VM0);   // stages A(NT-1); drain everything before last tile
  TILE(1, 0, NT - 1, false, false, (void)0);

#undef TILE
#undef BAR
#undef LGKM0
#undef VM4
#undef VM0
#undef MM_Q
#undef LDB_Q
#undef LDA_Q
#undef STG_B
#undef STG_A

  // C/D layout (verified): row = wm*128 + fi*16 + q*4 + rr, col = wn*64 + fj*16 + r
  if (!FUSED) {
    #pragma unroll
    for (int fi = 0; fi < 8; fi++) {
      #pragma unroll
      for (int fj = 0; fj < 4; fj++) {
        long col = n0 + wn * 64 + fj * 16 + r;
        float bj = bias[col];
        #pragma unroll
        for (int rr = 0; rr < 4; rr++) {
          long row = m0 + wm * 128 + fi * 16 + q * 4 + rr;
          C[row * ldc + col] = bf16r(acc[fi][fj][rr] * scale + bj);
        }
      }
    }
  } else {
    const float* vwz = vw + (long)z * SEQ + n0;
    float* numz = num + (long)z * SEQ + m0;
    float* denz = den + (long)z * SEQ + m0;
    float vwj[4];
    #pragma unroll
    for (int fj = 0; fj < 4; fj++) vwj[fj] = vwz[wn * 64 + fj * 16 + r];
    #pragma unroll
    for (int fi = 0; fi < 8; fi++) {
      #pragma unroll
      for (int rr = 0; rr < 4; rr++) {
        float sn = 0.f, sd = 0.f;
        #pragma unroll
        for (int fj = 0; fj < 4; fj++) {
          float e = __expf(acc[fi][fj][rr] * scale);
          sd += e;
          sn += e * vwj[fj];
        }
        #pragma unroll
        for (int off = 1; off < 16; off <<= 1) {
          sn += __shfl_xor(sn, off);
          sd += __shfl_xor(sd, off);
        }
        if (r == 0) {
          int row = wm * 128 + fi * 16 + q * 4 + rr;
          atomicAdd(&numz[row], sn);
          atomicAdd(&denz[row], sd);
        }
      }
    }
  }
}

// out[row] = num[row]/den[row] + c_eff
__global__ __launch_bounds__(256) void finalize(
    const float* __restrict__ num, const float* __restrict__ den,
    const float* __restrict__ sc, float* __restrict__ out) {
  long i = blockIdx.x * 256L + threadIdx.x;
  out[i] = num[i] / den[i] + sc[0];
}

extern "C" void kernel_launch(void* const* d_in, const int* in_sizes, int n_in,
                              void* d_out, int out_size, void* d_ws, size_t ws_size,
                              hipStream_t stream) {
  const float* x     = (const float*)d_in[0];
  const float* Wattn = (const float*)d_in[1];
  const float* battn = (const float*)d_in[2];
  const float* Wproj = (const float*)d_in[3];
  const float* bproj = (const float*)d_in[4];
  const float* Wfc   = (const float*)d_in[5];
  const float* bfc   = (const float*)d_in[6];
  float* out = (float*)d_out;

  // ws layout (bytes)
  const size_t OFF_XB    = 0;          // bf16 [16384][1024]  33554432
  const size_t OFF_WQKB  = 33554432;   // bf16 [2048][1024]    4194304
  const size_t OFF_QK    = 37748736;   // bf16 [16384][2048]  67108864
  const size_t OFF_NUM   = 104857600;  // f32  [16384]           65536
  const size_t OFF_DEN   = 104923136;  // f32  [16384]           65536
  const size_t OFF_VW    = 104988672;  // f32  [16384]           65536
  const size_t OFF_WEFF  = 105054208;  // f32  [1024]
  const size_t OFF_WVEFF = 105058304;  // f32  [1024]
  const size_t OFF_SC    = 105062400;  // f32  [2] {c_eff, vb_eff}
  const size_t NEED      = 105062408;
  if (ws_size < NEED) return;

  char* ws = (char*)d_ws;
  ushort* xb    = (ushort*)(ws + OFF_XB);
  ushort* wqkb  = (ushort*)(ws + OFF_WQKB);
  ushort* qk    = (ushort*)(ws + OFF_QK);
  float* num    = (float*)(ws + OFF_NUM);
  float* den    = (float*)(ws + OFF_DEN);
  float* vw     = (float*)(ws + OFF_VW);
  float* w_eff  = (float*)(ws + OFF_WEFF);
  float* wv_eff = (float*)(ws + OFF_WVEFF);
  float* sc     = (float*)(ws + OFF_SC);

  init_kernel<<<dim3(35), dim3(1024), 0, stream>>>(bproj, Wfc, bfc, w_eff, wv_eff, num, sc);
  prep1<<<dim3(4, 64), dim3(256), 0, stream>>>(Wproj, Wfc, w_eff);
  prep2<<<dim3(4, 65), dim3(256), 0, stream>>>(Wattn, battn, w_eff, wv_eff, sc);

  cvt_all<<<dim3(4096 + 512), dim3(256), 0, stream>>>(
      (const float4*)x, (const float4*)Wattn, (const float4*)wv_eff, sc, xb, wqkb, vw);

  // GEMM1 (REMAP=true): qk[m, n] = bf16( x[m,:] . Wattn[n,:] + battn[n] ), n in [0,2048)
  gemm_nt<false, true><<<dim3(8, 64, 1), dim3(512), 0, stream>>>(
      xb, (long)D_EMB, 0L, wqkb, (long)D_EMB, 0L,
      qk, 2048L, battn, 1.0f, D_EMB, nullptr, nullptr, nullptr);

  // GEMM2: fused num/den partial softmax sums (scale = 1/sqrt(1024))
  gemm_nt<true, false><<<dim3(8, 8, NBATCH), dim3(512), 0, stream>>>(
      qk, 2048L, (long)SEQ * 2048, qk + 1024, 2048L, (long)SEQ * 2048,
      nullptr, 0L, nullptr, 0.03125f, D_EMB, vw, num, den);

  finalize<<<dim3(64), dim3(256), 0, stream>>>(num, den, sc, out);
}